// Round 11
// baseline (144.950 us; speedup 1.0000x reference)
//
#include <hip/hip_runtime.h>
#include <math.h>

#define BB 16384      // B
#define CC 50         // clusters
#define KK 128        // top-K
#define DD 128        // feature dim
#define MM 12800      // CC*2*KK rows of F
#define NBLK 100      // 128-row blocks of F
#define NCHUNK 13     // J-chunks per row (chunk = 8 tiles)
#define CHT 8         // tiles per chunk
#define MAXCAND 2048
#define TCAND 0.97f
#define NPART 64      // candidate partitions (256 rows each)
#define RPP 256       // rows per partition
#define PCAP 32       // per (partition,cluster) capacity; expected ~7.7
// F rows pre-scaled by SQS = sqrt(2/ln2): dot(F,F) = sim*2/ln2 -> exp2 direct.
// Single bf16 product (validated r8-r10: absmax 0.0 vs reference).
#define SQS 1.6986436f

// Tiled F layout: for each 32-row group G (400 groups), each kc (16-K chunk,
// 8 chunks), 64 granules of 16B lane-ordered for mfma_32x32x16_bf16 operands.
// One fragment load = contiguous 1KB wave load at G*8192 + kc*1024 + lane*16.

typedef __bf16 bf16x8 __attribute__((ext_vector_type(8)));
typedef float f32x16 __attribute__((ext_vector_type(16)));

#define MFMA32(a, b, c) __builtin_amdgcn_mfma_f32_32x32x16_bf16(a, b, c, 0, 0, 0)

__device__ inline unsigned short f2bf(float x) {
  unsigned u = __float_as_uint(x);
  unsigned r = (u + 0x7fffu + ((u >> 16) & 1u)) >> 16;
  return (unsigned short)r;
}

// ---------------------------------------------------------------------------
// Kernel 1: candidate collection, zero global atomics (r9, validated).
// Also zeroes the finalize ticket for this launch.
// ---------------------------------------------------------------------------
__global__ void cand_kernel(const float* __restrict__ prob, int* __restrict__ candCnt,
                            int* __restrict__ candIdx, float* __restrict__ candVal,
                            int* __restrict__ ticket) {
  __shared__ int lcnt[CC];
  const int b = blockIdx.x, t = threadIdx.x;
  if (b == 0 && t == 0) *ticket = 0;
  if (t < CC) lcnt[t] = 0;
  __syncthreads();
  const int base = b * RPP * CC;
  for (int i = t; i < RPP * CC; i += 256) {
    const float v = prob[base + i];
    if (v >= TCAND) {
      const int r = i / CC, c = i - r * CC;
      const int slot = atomicAdd(&lcnt[c], 1);
      if (slot < PCAP) {
        candIdx[(b * CC + c) * PCAP + slot] = b * RPP + r;
        candVal[(b * CC + c) * PCAP + slot] = v;
      }
    }
  }
  __syncthreads();
  if (t < CC) candCnt[b * CC + t] = lcnt[t];
}

// ---------------------------------------------------------------------------
// Kernel 2: FUSED per-cluster top-K select + row gather/normalize.
// One block per cluster. Phase 1: coalesced candidate gather into LDS +
// radix select -> topkL[128] (LDS). Phase 2: thread t gathers row t of the
// cluster (zi for t<128, zj else), serial-FMA norm, SQS scale, bf16 pack,
// coalesced uint4 writes into tiled F. Exact fallback preserved.
// ---------------------------------------------------------------------------
__global__ void selgather_kernel(const float* __restrict__ prob,
                                 const int* __restrict__ candCnt,
                                 const int* __restrict__ candIdx,
                                 const float* __restrict__ candVal,
                                 const float* __restrict__ zi,
                                 const float* __restrict__ zj,
                                 char* __restrict__ FT) {
  __shared__ float vals[MAXCAND];
  __shared__ int   idxs[MAXCAND];
  __shared__ int hist[256];
  __shared__ int pref[NPART + 1];
  __shared__ int cntL[NPART];
  __shared__ int topkL[KK];
  __shared__ int eqIdx[256];
  __shared__ int sChosen, sKrem, gtc, eqc, bad;
  const int c = blockIdx.x, t = threadIdx.x;

  if (t == 0) bad = 0;
  __syncthreads();
  if (t < NPART) {
    int cnt_p = candCnt[t * CC + c];
    cntL[t] = cnt_p;
    if (cnt_p > PCAP) bad = 1;
    int x = cnt_p;
#pragma unroll
    for (int d = 1; d < 64; d <<= 1) {
      int y = __shfl_up(x, d, 64);
      if (t >= d) x += y;
    }
    pref[t + 1] = x;
    if (t == 0) pref[0] = 0;
  }
  __syncthreads();
  const int total = pref[NPART];

  if (!bad && total >= KK && total <= MAXCAND) {
    // ---- coalesced gather of all candidates into LDS ----
    for (int idx = t; idx < NPART * PCAP; idx += 256) {
      const int pt = idx >> 5, sl = idx & 31;
      if (sl < cntL[pt]) {
        const int o = pref[pt] + sl;
        vals[o] = candVal[(pt * CC + c) * PCAP + sl];
        idxs[o] = candIdx[(pt * CC + c) * PCAP + sl];
      }
    }
    __syncthreads();
    unsigned prefix = 0;
    int krem = KK;
    for (int pass = 0; pass < 4; ++pass) {
      const int shift = 24 - pass * 8;
      hist[t] = 0;
      __syncthreads();
      for (int j = t; j < total; j += 256) {
        unsigned u = __float_as_uint(vals[j]);
        bool match = (pass == 0) || ((u >> (shift + 8)) == (prefix >> (shift + 8)));
        if (match) atomicAdd(&hist[(u >> shift) & 255], 1);
      }
      __syncthreads();
      if (t == 0) {
        int kr = krem, b2 = 255;
        for (; b2 > 0; --b2) {
          if (kr > hist[b2]) kr -= hist[b2];
          else break;
        }
        sChosen = b2; sKrem = kr;
      }
      __syncthreads();
      prefix |= ((unsigned)sChosen) << shift;
      krem = sKrem;
      __syncthreads();
    }
    const unsigned T = prefix;
    if (t == 0) { gtc = 0; eqc = 0; }
    __syncthreads();
    for (int j = t; j < total; j += 256) {
      unsigned u = __float_as_uint(vals[j]);
      if (u > T) {
        int pos = atomicAdd(&gtc, 1);
        topkL[pos] = idxs[j];
      } else if (u == T) {
        int e = atomicAdd(&eqc, 1);
        if (e < 256) eqIdx[e] = idxs[j];
      }
    }
    __syncthreads();
    if (t == 0) {
      int base = gtc;
      int ec = eqc < 256 ? eqc : 256;
      for (int j2 = 0; j2 < krem; ++j2) {
        int bi = -1, bv = 0x7fffffff;
        for (int q = 0; q < ec; ++q) {
          int v = eqIdx[q];
          if (v >= 0 && v < bv) { bv = v; bi = q; }
        }
        topkL[base + j2] = bv;
        eqIdx[bi] = -1;
      }
    }
  } else {
    // ---- exact fallback: full strided column radix select ----
    unsigned prefix = 0;
    int krem = KK;
    for (int pass = 0; pass < 4; ++pass) {
      const int shift = 24 - pass * 8;
      hist[t] = 0;
      __syncthreads();
      for (int i = t; i < BB; i += 256) {
        unsigned u = __float_as_uint(prob[i * CC + c]);
        bool match = (pass == 0) || ((u >> (shift + 8)) == (prefix >> (shift + 8)));
        if (match) atomicAdd(&hist[(u >> shift) & 255], 1);
      }
      __syncthreads();
      if (t == 0) {
        int kr = krem, b2 = 255;
        for (; b2 > 0; --b2) {
          if (kr > hist[b2]) kr -= hist[b2];
          else break;
        }
        sChosen = b2; sKrem = kr;
      }
      __syncthreads();
      prefix |= ((unsigned)sChosen) << shift;
      krem = sKrem;
      __syncthreads();
    }
    const unsigned T = prefix;
    if (t == 0) { gtc = 0; eqc = 0; }
    __syncthreads();
    for (int i = t; i < BB; i += 256) {
      unsigned u = __float_as_uint(prob[i * CC + c]);
      if (u > T) {
        int pos = atomicAdd(&gtc, 1);
        topkL[pos] = i;
      } else if (u == T) {
        int e = atomicAdd(&eqc, 1);
        if (e < 256) eqIdx[e] = i;
      }
    }
    __syncthreads();
    if (t == 0) {
      int base = gtc;
      int ec = eqc < 256 ? eqc : 256;
      for (int j = 0; j < krem; ++j) {
        int bi = -1, bv = 0x7fffffff;
        for (int q = 0; q < ec; ++q) {
          int v = eqIdx[q];
          if (v >= 0 && v < bv) { bv = v; bi = q; }
        }
        topkL[base + j] = bv;
        eqIdx[bi] = -1;
      }
    }
  }

  // ---- Phase 2: gather + normalize + tiled bf16 write; thread t = row t ----
  __syncthreads();
  const int p = t;
  const int idx = topkL[p & (KK - 1)];
  const float* src = (p < KK ? zi : zj) + (size_t)idx * DD;
  const float4* s4 = (const float4*)src;
  float ss = 0.f;
#pragma unroll
  for (int i = 0; i < 32; ++i) {
    float4 f = s4[i];
    ss = fmaf(f.x, f.x, fmaf(f.y, f.y, fmaf(f.z, f.z, fmaf(f.w, f.w, ss))));
  }
  const float scale = SQS / fmaxf(sqrtf(ss), 1e-8f);
  const int gw = c * 256 + p;
  char* dst = FT + (size_t)(gw >> 5) * 8192 + (size_t)(gw & 31) * 16;
#pragma unroll
  for (int kc = 0; kc < 8; ++kc)
#pragma unroll
    for (int half = 0; half < 2; ++half) {
      float4 fa = s4[kc * 4 + half * 2];
      float4 fb = s4[kc * 4 + half * 2 + 1];
      uint4 w;
      w.x = ((unsigned)f2bf(fa.y * scale) << 16) | f2bf(fa.x * scale);
      w.y = ((unsigned)f2bf(fa.w * scale) << 16) | f2bf(fa.z * scale);
      w.z = ((unsigned)f2bf(fb.y * scale) << 16) | f2bf(fb.x * scale);
      w.w = ((unsigned)f2bf(fb.w * scale) << 16) | f2bf(fb.z * scale);
      *(uint4*)(dst + kc * 1024 + half * 512) = w;
    }
}

// ---------------------------------------------------------------------------
// Kernel 3: PANELIZED symmetric sim (r10, validated).
// ---------------------------------------------------------------------------
__global__ __launch_bounds__(128, 2) void sim_sym_kernel(
    const char* __restrict__ F, float* __restrict__ part,
    float* __restrict__ ownArr, float* __restrict__ posArr) {
  __shared__ float colLds[2][1024];
  const int tid = threadIdx.x;
  const int lane = tid & 63, wave = tid >> 6;
  const int lh2 = lane >> 5;
  const size_t lo16 = (size_t)lane * 16;

  f32x16 Z = {};

#define LOADB(BUF, GIDX) {                                                     \
    _Pragma("unroll")                                                          \
    for (int kc = 0; kc < 8; ++kc)                                             \
      BUF[kc] = *(const bf16x8*)(F + (size_t)(GIDX) * 8192 + kc * 1024 + lo16);\
  }

  if (blockIdx.x < NBLK * NCHUNK) {
    const int I = blockIdx.x / NCHUNK, q = blockIdx.x - I * NCHUNK;
    const int J0 = I + q * CHT;
    if (J0 >= NBLK) return;
    const int nt = min(CHT, NBLK - J0);
    const int S = nt * 4;
    const int G0 = J0 * 4;
    const int Ga = I * 4 + wave * 2;

    bf16x8 A0[8], A1[8];
#pragma unroll
    for (int kc = 0; kc < 8; ++kc) {
      A0[kc] = *(const bf16x8*)(F + (size_t)Ga * 8192 + kc * 1024 + lo16);
      A1[kc] = *(const bf16x8*)(F + (size_t)(Ga + 1) * 8192 + kc * 1024 + lo16);
    }
    bf16x8 b0[8], b1[8];
    f32x16 aA0, aA1, aB0, aB1;
    float rAcc0[16], rAcc1[16];
#pragma unroll
    for (int r = 0; r < 16; ++r) { rAcc0[r] = 0.f; rAcc1[r] = 0.f; }
    float colv = 0.f;

#define PROC(AC0, AC1, BB_, AP0, AP1)                                          \
    AC0 = MFMA32(A0[0], BB_[0], Z); AC1 = MFMA32(A1[0], BB_[0], Z);            \
    _Pragma("unroll")                                                          \
    for (int kc = 1; kc < 8; ++kc) {                                           \
      AC0 = MFMA32(A0[kc], BB_[kc], AC0);                                      \
      AC1 = MFMA32(A1[kc], BB_[kc], AC1);                                      \
      const int r0 = 2 * (kc - 1), r1 = r0 + 1;                                \
      float e0 = __builtin_amdgcn_exp2f(AP0[r0]);                              \
      float e1 = __builtin_amdgcn_exp2f(AP0[r1]);                              \
      float e2 = __builtin_amdgcn_exp2f(AP1[r0]);                              \
      float e3 = __builtin_amdgcn_exp2f(AP1[r1]);                              \
      rAcc0[r0] += e0; rAcc0[r1] += e1; rAcc1[r0] += e2; rAcc1[r1] += e3;      \
      colv += (e0 + e1) + (e2 + e3);                                           \
    }                                                                          \
    { float e0 = __builtin_amdgcn_exp2f(AP0[14]);                              \
      float e1 = __builtin_amdgcn_exp2f(AP0[15]);                              \
      float e2 = __builtin_amdgcn_exp2f(AP1[14]);                              \
      float e3 = __builtin_amdgcn_exp2f(AP1[15]);                              \
      rAcc0[14] += e0; rAcc0[15] += e1; rAcc1[14] += e2; rAcc1[15] += e3;      \
      colv += (e0 + e1) + (e2 + e3); }

#define FINCOL(S_) {                                                           \
    float cv = colv + __shfl_xor(colv, 32, 64);                                \
    if (lane < 32) colLds[wave][(S_) * 32 + lane] = cv;                        \
    colv = 0.f; }

    LOADB(b0, G0)
    aA0 = MFMA32(A0[0], b0[0], Z); aA1 = MFMA32(A1[0], b0[0], Z);
#pragma unroll
    for (int kc = 1; kc < 8; ++kc) {
      aA0 = MFMA32(A0[kc], b0[kc], aA0);
      aA1 = MFMA32(A1[kc], b0[kc], aA1);
    }
    LOADB(b1, G0 + 1)

    int s = 1;
    for (; s + 1 < S; s += 2) {
      PROC(aB0, aB1, b1, aA0, aA1)
      FINCOL(s - 1)
      LOADB(b0, G0 + s + 1)
      PROC(aA0, aA1, b0, aB0, aB1)
      FINCOL(s)
      LOADB(b1, G0 + s + 2)
    }
    PROC(aB0, aB1, b1, aA0, aA1)
    FINCOL(S - 2)
#pragma unroll
    for (int r = 0; r < 16; ++r) {
      float e0 = __builtin_amdgcn_exp2f(aB0[r]);
      float e1 = __builtin_amdgcn_exp2f(aB1[r]);
      rAcc0[r] += e0; rAcc1[r] += e1;
      colv += e0 + e1;
    }
    FINCOL(S - 1)
#undef PROC
#undef FINCOL

    __syncthreads();
    for (int idx = tid; idx < S * 32; idx += 128) {
      const int J = J0 + (idx >> 7);
      if (J != I)
        part[(size_t)I * MM + J * 128 + (idx & 127)] = colLds[0][idx] + colLds[1][idx];
    }

#pragma unroll
    for (int m = 1; m < 32; m <<= 1)
#pragma unroll
      for (int r = 0; r < 16; ++r) {
        rAcc0[r] += __shfl_xor(rAcc0[r], m, 32);
        rAcc1[r] += __shfl_xor(rAcc1[r], m, 32);
      }
    if ((lane & 31) == 0) {
      const int rbase = I * 128 + wave * 64;
#pragma unroll
      for (int r = 0; r < 16; ++r) {
        const int rl = (r & 3) + 8 * (r >> 2) + 4 * lh2;
        part[(size_t)(NBLK + q) * MM + rbase + rl] = rAcc0[r];
        part[(size_t)(NBLK + q) * MM + rbase + 32 + rl] = rAcc1[r];
      }
    }
  } else {
    // ================= own/pos path (r9, validated) =================
    const int bid2 = blockIdx.x - NBLK * NCHUNK;
    const int c = bid2 >> 1, q2 = bid2 & 1;
    const int Ga = c * 8 + q2 * 4 + wave * 2;
    const int c8 = c * 8;

    bf16x8 A0[8], A1[8];
#pragma unroll
    for (int kc = 0; kc < 8; ++kc) {
      A0[kc] = *(const bf16x8*)(F + (size_t)Ga * 8192 + kc * 1024 + lo16);
      A1[kc] = *(const bf16x8*)(F + (size_t)(Ga + 1) * 8192 + kc * 1024 + lo16);
    }
    bf16x8 b0[8], b1[8];
    float rAcc0[16], rAcc1[16];
#pragma unroll
    for (int r = 0; r < 16; ++r) { rAcc0[r] = 0.f; rAcc1[r] = 0.f; }

#define OWNTILE(BB_) {                                                         \
    f32x16 a0 = MFMA32(A0[0], BB_[0], Z), a1 = MFMA32(A1[0], BB_[0], Z);       \
    _Pragma("unroll")                                                          \
    for (int kc = 1; kc < 8; ++kc) {                                           \
      a0 = MFMA32(A0[kc], BB_[kc], a0); a1 = MFMA32(A1[kc], BB_[kc], a1); }    \
    _Pragma("unroll")                                                          \
    for (int r = 0; r < 16; ++r) {                                             \
      rAcc0[r] += __builtin_amdgcn_exp2f(a0[r]);                               \
      rAcc1[r] += __builtin_amdgcn_exp2f(a1[r]); } }

#define REDUCEW(DST) {                                                         \
    float t0[16], t1[16];                                                      \
    _Pragma("unroll")                                                          \
    for (int r = 0; r < 16; ++r) { t0[r] = rAcc0[r]; t1[r] = rAcc1[r]; }       \
    _Pragma("unroll")                                                          \
    for (int m = 1; m < 32; m <<= 1)                                           \
      _Pragma("unroll")                                                        \
      for (int r = 0; r < 16; ++r) {                                           \
        t0[r] += __shfl_xor(t0[r], m, 32);                                     \
        t1[r] += __shfl_xor(t1[r], m, 32); }                                   \
    if ((lane & 31) == 0) {                                                    \
      const int rbase = c * 256 + q2 * 128 + wave * 64;                        \
      _Pragma("unroll")                                                        \
      for (int r = 0; r < 16; ++r) {                                           \
        const int rl = (r & 3) + 8 * (r >> 2) + 4 * lh2;                       \
        DST[rbase + rl] = t0[r];                                               \
        DST[rbase + 32 + rl] = t1[r]; } } }

    LOADB(b0, c8 + 0)
    LOADB(b1, c8 + 1)  OWNTILE(b0)
    LOADB(b0, c8 + 2)  OWNTILE(b1)
    LOADB(b1, c8 + 3)  OWNTILE(b0)
    LOADB(b0, c8 + 4)  OWNTILE(b1)
    REDUCEW(posArr)
    LOADB(b1, c8 + 5)  OWNTILE(b0)
    LOADB(b0, c8 + 6)  OWNTILE(b1)
    LOADB(b1, c8 + 7)  OWNTILE(b0)
    OWNTILE(b1)
    REDUCEW(ownArr)
#undef OWNTILE
#undef REDUCEW
  }
#undef LOADB
}

// ---------------------------------------------------------------------------
// Kernel 4: per-row loss + block reduction + last-block mean (ticket).
// ---------------------------------------------------------------------------
__global__ void finalize_kernel(const float* __restrict__ part,
                                const float* __restrict__ ownArr,
                                const float* __restrict__ posArr,
                                float* __restrict__ partial,
                                int* __restrict__ ticket,
                                float* __restrict__ out) {
  __shared__ float red[4];
  const int t = threadIdx.x;
  const int p = blockIdx.x * 256 + t;
  const int pb = p >> 7;
  float a = 0.f;
  for (int b = 0; b < pb; ++b) a += part[(size_t)b * MM + p];
  const int qmax = (NBLK - 1 - pb) >> 3;
  for (int q = 0; q <= qmax; ++q) a += part[(size_t)(NBLK + q) * MM + p];
  float rl = logf(a - ownArr[p]) - logf(posArr[p]);
#pragma unroll
  for (int m = 1; m < 64; m <<= 1) rl += __shfl_xor(rl, m, 64);
  if ((t & 63) == 0) red[t >> 6] = rl;
  __syncthreads();
  if (t == 0) {
    const float bsum = red[0] + red[1] + red[2] + red[3];
    __hip_atomic_store(&partial[blockIdx.x], bsum, __ATOMIC_RELEASE,
                       __HIP_MEMORY_SCOPE_AGENT);
    const int old = __hip_atomic_fetch_add(ticket, 1, __ATOMIC_ACQ_REL,
                                           __HIP_MEMORY_SCOPE_AGENT);
    if (old == (MM / 256) - 1) {          // last block: deterministic sum
      float s = 0.f;
      for (int i = 0; i < MM / 256; ++i)
        s += __hip_atomic_load(&partial[i], __ATOMIC_ACQUIRE,
                               __HIP_MEMORY_SCOPE_AGENT);
      out[0] = s * (1.0f / MM);
    }
  }
}

extern "C" void kernel_launch(void* const* d_in, const int* in_sizes, int n_in,
                              void* d_out, int out_size, void* d_ws, size_t ws_size,
                              hipStream_t stream) {
  const float* prob = (const float*)d_in[0];
  const float* zi   = (const float*)d_in[1];
  const float* zj   = (const float*)d_in[2];
  float* out = (float*)d_out;

  char* ws = (char*)d_ws;
  char*  FT       = ws;                                  // 3,276,800 B
  float* part     = (float*)(ws + 3276800);              // 113*12800*4 = 5,785,600 B
  // cand buffers alias the (not-yet-live) part region: dead before sim writes.
  int*   candCnt  = (int*)  (ws + 3276800);              //    12,800 B
  int*   candIdx  = (int*)  (ws + 3276800 + 16384);      //   409,600 B
  float* candVal  = (float*)(ws + 3276800 + 430080);     //   409,600 B
  float* ownArr   = (float*)(ws + 9062400);              //    51,200 B
  float* posArr   = (float*)(ws + 9113600);              //    51,200 B
  float* partial  = (float*)(ws + 9164800);              //       256 B
  int*   ticket   = (int*)  (ws + 9165056);              //         4 B

  cand_kernel     <<<NPART, 256, 0, stream>>>(prob, candCnt, candIdx, candVal, ticket);
  selgather_kernel<<<CC, 256, 0, stream>>>(prob, candCnt, candIdx, candVal, zi, zj, FT);
  sim_sym_kernel  <<<NBLK * NCHUNK + 2 * CC, 128, 0, stream>>>(FT, part, ownArr, posArr);
  finalize_kernel <<<MM / 256, 256, 0, stream>>>(part, ownArr, posArr, partial, ticket, out);
}

// Round 12
// 109.195 us; speedup vs baseline: 1.3274x; 1.3274x over previous
//
#include <hip/hip_runtime.h>
#include <math.h>

#define BB 16384      // B
#define CC 50         // clusters
#define KK 128        // top-K
#define DD 128        // feature dim
#define MM 12800      // CC*2*KK rows of F
#define NBLK 100      // 128-row blocks of F
#define NCHUNK 13     // J-chunks per row (chunk = 8 tiles)
#define CHT 8         // tiles per chunk
#define MAXCAND 2048
#define TCAND 0.97f
#define NPART 64      // candidate partitions (256 rows each)
#define RPP 256       // rows per partition
#define PCAP 32       // per (partition,cluster) capacity; expected ~7.7
// F rows pre-scaled by SQS = sqrt(2/ln2): dot(F,F) = sim*2/ln2 -> exp2 direct.
// Single bf16 product (validated r8-r11: absmax 0.0 vs reference).
#define SQS 1.6986436f

// Tiled F layout: for each 32-row group G (400 groups), each kc (16-K chunk,
// 8 chunks), 64 granules of 16B lane-ordered for mfma_32x32x16_bf16 operands.
// One fragment load = contiguous 1KB wave load at G*8192 + kc*1024 + lane*16.

typedef __bf16 bf16x8 __attribute__((ext_vector_type(8)));
typedef float f32x16 __attribute__((ext_vector_type(16)));

#define MFMA32(a, b, c) __builtin_amdgcn_mfma_f32_32x32x16_bf16(a, b, c, 0, 0, 0)

__device__ inline unsigned short f2bf(float x) {
  unsigned u = __float_as_uint(x);
  unsigned r = (u + 0x7fffu + ((u >> 16) & 1u)) >> 16;
  return (unsigned short)r;
}

// ---------------------------------------------------------------------------
// Kernel 1: candidate collection, zero global atomics (r9, validated).
// Also zeroes the finalize ticket for this launch.
// ---------------------------------------------------------------------------
__global__ void cand_kernel(const float* __restrict__ prob, int* __restrict__ candCnt,
                            int* __restrict__ candIdx, float* __restrict__ candVal,
                            int* __restrict__ ticket) {
  __shared__ int lcnt[CC];
  const int b = blockIdx.x, t = threadIdx.x;
  if (b == 0 && t == 0) *ticket = 0;
  if (t < CC) lcnt[t] = 0;
  __syncthreads();
  const int base = b * RPP * CC;
  for (int i = t; i < RPP * CC; i += 256) {
    const float v = prob[base + i];
    if (v >= TCAND) {
      const int r = i / CC, c = i - r * CC;
      const int slot = atomicAdd(&lcnt[c], 1);
      if (slot < PCAP) {
        candIdx[(b * CC + c) * PCAP + slot] = b * RPP + r;
        candVal[(b * CC + c) * PCAP + slot] = v;
      }
    }
  }
  __syncthreads();
  if (t < CC) candCnt[b * CC + t] = lcnt[t];
}

// ---------------------------------------------------------------------------
// PARALLEL bin selection: hist[256] -> suffix sums in place (8-step ladder),
// then the unique crossing thread (S[b] >= krem > S[b+1]) picks the bin.
// Replaces the t==0 serial ~200-dependent-LDS-read scan (~12 us/pass!).
// Serial equivalent: kr=krem; for b=255..: if kr>hist[b] kr-=hist[b] else stop
//  -> chosen = max{b : S[b] >= krem}, new krem = krem - S[chosen+1].
// ---------------------------------------------------------------------------
#define PICK_BIN()                                                             \
  {                                                                            \
    _Pragma("unroll")                                                          \
    for (int d = 1; d < 256; d <<= 1) {                                        \
      int v = (t + d < 256) ? hist[t + d] : 0;                                 \
      __syncthreads();                                                         \
      hist[t] += v;                                                            \
      __syncthreads();                                                         \
    }                                                                          \
    const int Sb = hist[t];                                                    \
    const int Sb1 = (t == 255) ? 0 : hist[t + 1];                              \
    if (Sb >= krem && Sb1 < krem) { sChosen = t; sKrem = krem - Sb1; }         \
    __syncthreads();                                                           \
  }

// ---------------------------------------------------------------------------
// Kernel 2: per-cluster exact top-K with parallel radix select.
// ---------------------------------------------------------------------------
__global__ void select_kernel(const float* __restrict__ prob,
                              const int* __restrict__ candCnt,
                              const int* __restrict__ candIdx,
                              const float* __restrict__ candVal,
                              int* __restrict__ topk) {
  __shared__ float vals[MAXCAND];
  __shared__ int   idxs[MAXCAND];
  __shared__ int hist[256];
  __shared__ int pref[NPART + 1];
  __shared__ int cntL[NPART];
  __shared__ int eqIdx[256];
  __shared__ int sChosen, sKrem, gtc, eqc, bad;
  const int c = blockIdx.x, t = threadIdx.x;

  if (t == 0) bad = 0;
  __syncthreads();
  if (t < NPART) {
    int cnt_p = candCnt[t * CC + c];
    cntL[t] = cnt_p;
    if (cnt_p > PCAP) bad = 1;
    int x = cnt_p;
#pragma unroll
    for (int d = 1; d < 64; d <<= 1) {
      int y = __shfl_up(x, d, 64);
      if (t >= d) x += y;
    }
    pref[t + 1] = x;
    if (t == 0) pref[0] = 0;
  }
  __syncthreads();
  const int total = pref[NPART];

  if (!bad && total >= KK && total <= MAXCAND) {
    // ---- coalesced candidate gather into LDS (r11, validated) ----
    for (int idx = t; idx < NPART * PCAP; idx += 256) {
      const int pt = idx >> 5, sl = idx & 31;
      if (sl < cntL[pt]) {
        const int o = pref[pt] + sl;
        vals[o] = candVal[(pt * CC + c) * PCAP + sl];
        idxs[o] = candIdx[(pt * CC + c) * PCAP + sl];
      }
    }
    __syncthreads();
    unsigned prefix = 0;
    int krem = KK;
    for (int pass = 0; pass < 4; ++pass) {
      const int shift = 24 - pass * 8;
      hist[t] = 0;
      __syncthreads();
      for (int j = t; j < total; j += 256) {
        unsigned u = __float_as_uint(vals[j]);
        bool match = (pass == 0) || ((u >> (shift + 8)) == (prefix >> (shift + 8)));
        if (match) atomicAdd(&hist[(u >> shift) & 255], 1);
      }
      __syncthreads();
      PICK_BIN()
      prefix |= ((unsigned)sChosen) << shift;
      krem = sKrem;
      __syncthreads();
    }
    const unsigned T = prefix;
    if (t == 0) { gtc = 0; eqc = 0; }
    __syncthreads();
    for (int j = t; j < total; j += 256) {
      unsigned u = __float_as_uint(vals[j]);
      if (u > T) {
        int pos = atomicAdd(&gtc, 1);
        topk[c * KK + pos] = idxs[j];
      } else if (u == T) {
        int e = atomicAdd(&eqc, 1);
        if (e < 256) eqIdx[e] = idxs[j];
      }
    }
    __syncthreads();
    if (t == 0) {
      int base = gtc;
      int ec = eqc < 256 ? eqc : 256;
      for (int j2 = 0; j2 < krem; ++j2) {
        int bi = -1, bv = 0x7fffffff;
        for (int q = 0; q < ec; ++q) {
          int v = eqIdx[q];
          if (v >= 0 && v < bv) { bv = v; bi = q; }
        }
        topk[c * KK + base + j2] = bv;
        eqIdx[bi] = -1;
      }
    }
  } else {
    // ---- exact fallback: full strided column radix select ----
    unsigned prefix = 0;
    int krem = KK;
    for (int pass = 0; pass < 4; ++pass) {
      const int shift = 24 - pass * 8;
      hist[t] = 0;
      __syncthreads();
      for (int i = t; i < BB; i += 256) {
        unsigned u = __float_as_uint(prob[i * CC + c]);
        bool match = (pass == 0) || ((u >> (shift + 8)) == (prefix >> (shift + 8)));
        if (match) atomicAdd(&hist[(u >> shift) & 255], 1);
      }
      __syncthreads();
      PICK_BIN()
      prefix |= ((unsigned)sChosen) << shift;
      krem = sKrem;
      __syncthreads();
    }
    const unsigned T = prefix;
    if (t == 0) { gtc = 0; eqc = 0; }
    __syncthreads();
    for (int i = t; i < BB; i += 256) {
      unsigned u = __float_as_uint(prob[i * CC + c]);
      if (u > T) {
        int pos = atomicAdd(&gtc, 1);
        topk[c * KK + pos] = i;
      } else if (u == T) {
        int e = atomicAdd(&eqc, 1);
        if (e < 256) eqIdx[e] = i;
      }
    }
    __syncthreads();
    if (t == 0) {
      int base = gtc;
      int ec = eqc < 256 ? eqc : 256;
      for (int j = 0; j < krem; ++j) {
        int bi = -1, bv = 0x7fffffff;
        for (int q = 0; q < ec; ++q) {
          int v = eqIdx[q];
          if (v >= 0 && v < bv) { bv = v; bi = q; }
        }
        topk[c * KK + base + j] = bv;
        eqIdx[bi] = -1;
      }
    }
  }
}

// ---------------------------------------------------------------------------
// Kernel 3: gather + L2-normalize + SQS scale + bf16, tiled layout.
// Wave per row, coalesced (r10, validated).
// ---------------------------------------------------------------------------
__global__ void gather_norm(const float* __restrict__ zi, const float* __restrict__ zj,
                            const int* __restrict__ topk, char* __restrict__ FT) {
  const int gw = (blockIdx.x * 256 + threadIdx.x) >> 6;
  const int lane = threadIdx.x & 63;
  if (gw >= MM) return;
  const int c = gw >> 8, p = gw & 255;
  const int idx = topk[c * KK + (p & (KK - 1))];
  const float* src = (p < KK ? zi : zj) + (size_t)idx * DD;
  float2 v = ((const float2*)src)[lane];
  float ss = fmaf(v.x, v.x, v.y * v.y);
#pragma unroll
  for (int m = 1; m < 64; m <<= 1) ss += __shfl_xor(ss, m, 64);
  const float scale = SQS / fmaxf(sqrtf(ss), 1e-8f);
  unsigned short ah = f2bf(v.x * scale), bh = f2bf(v.y * scale);
  unsigned hp = ((unsigned)bh << 16) | ah;
  const int k2 = 2 * lane;
  const int kc = k2 >> 4;
  const int kk = k2 & 15;
  const size_t off = (size_t)(gw >> 5) * 8192 + (size_t)kc * 1024 +
                     (size_t)(((kk >> 3) * 32 + (gw & 31)) * 16 + (kk & 7) * 2);
  *(unsigned*)(FT + off) = hp;
}

// ---------------------------------------------------------------------------
// Kernel 4: PANELIZED symmetric sim (r10, validated).
// ---------------------------------------------------------------------------
__global__ __launch_bounds__(128, 2) void sim_sym_kernel(
    const char* __restrict__ F, float* __restrict__ part,
    float* __restrict__ ownArr, float* __restrict__ posArr) {
  __shared__ float colLds[2][1024];
  const int tid = threadIdx.x;
  const int lane = tid & 63, wave = tid >> 6;
  const int lh2 = lane >> 5;
  const size_t lo16 = (size_t)lane * 16;

  f32x16 Z = {};

#define LOADB(BUF, GIDX) {                                                     \
    _Pragma("unroll")                                                          \
    for (int kc = 0; kc < 8; ++kc)                                             \
      BUF[kc] = *(const bf16x8*)(F + (size_t)(GIDX) * 8192 + kc * 1024 + lo16);\
  }

  if (blockIdx.x < NBLK * NCHUNK) {
    const int I = blockIdx.x / NCHUNK, q = blockIdx.x - I * NCHUNK;
    const int J0 = I + q * CHT;
    if (J0 >= NBLK) return;
    const int nt = min(CHT, NBLK - J0);
    const int S = nt * 4;
    const int G0 = J0 * 4;
    const int Ga = I * 4 + wave * 2;

    bf16x8 A0[8], A1[8];
#pragma unroll
    for (int kc = 0; kc < 8; ++kc) {
      A0[kc] = *(const bf16x8*)(F + (size_t)Ga * 8192 + kc * 1024 + lo16);
      A1[kc] = *(const bf16x8*)(F + (size_t)(Ga + 1) * 8192 + kc * 1024 + lo16);
    }
    bf16x8 b0[8], b1[8];
    f32x16 aA0, aA1, aB0, aB1;
    float rAcc0[16], rAcc1[16];
#pragma unroll
    for (int r = 0; r < 16; ++r) { rAcc0[r] = 0.f; rAcc1[r] = 0.f; }
    float colv = 0.f;

#define PROC(AC0, AC1, BB_, AP0, AP1)                                          \
    AC0 = MFMA32(A0[0], BB_[0], Z); AC1 = MFMA32(A1[0], BB_[0], Z);            \
    _Pragma("unroll")                                                          \
    for (int kc = 1; kc < 8; ++kc) {                                           \
      AC0 = MFMA32(A0[kc], BB_[kc], AC0);                                      \
      AC1 = MFMA32(A1[kc], BB_[kc], AC1);                                      \
      const int r0 = 2 * (kc - 1), r1 = r0 + 1;                                \
      float e0 = __builtin_amdgcn_exp2f(AP0[r0]);                              \
      float e1 = __builtin_amdgcn_exp2f(AP0[r1]);                              \
      float e2 = __builtin_amdgcn_exp2f(AP1[r0]);                              \
      float e3 = __builtin_amdgcn_exp2f(AP1[r1]);                              \
      rAcc0[r0] += e0; rAcc0[r1] += e1; rAcc1[r0] += e2; rAcc1[r1] += e3;      \
      colv += (e0 + e1) + (e2 + e3);                                           \
    }                                                                          \
    { float e0 = __builtin_amdgcn_exp2f(AP0[14]);                              \
      float e1 = __builtin_amdgcn_exp2f(AP0[15]);                              \
      float e2 = __builtin_amdgcn_exp2f(AP1[14]);                              \
      float e3 = __builtin_amdgcn_exp2f(AP1[15]);                              \
      rAcc0[14] += e0; rAcc0[15] += e1; rAcc1[14] += e2; rAcc1[15] += e3;      \
      colv += (e0 + e1) + (e2 + e3); }

#define FINCOL(S_) {                                                           \
    float cv = colv + __shfl_xor(colv, 32, 64);                                \
    if (lane < 32) colLds[wave][(S_) * 32 + lane] = cv;                        \
    colv = 0.f; }

    LOADB(b0, G0)
    aA0 = MFMA32(A0[0], b0[0], Z); aA1 = MFMA32(A1[0], b0[0], Z);
#pragma unroll
    for (int kc = 1; kc < 8; ++kc) {
      aA0 = MFMA32(A0[kc], b0[kc], aA0);
      aA1 = MFMA32(A1[kc], b0[kc], aA1);
    }
    LOADB(b1, G0 + 1)

    int s = 1;
    for (; s + 1 < S; s += 2) {
      PROC(aB0, aB1, b1, aA0, aA1)
      FINCOL(s - 1)
      LOADB(b0, G0 + s + 1)
      PROC(aA0, aA1, b0, aB0, aB1)
      FINCOL(s)
      LOADB(b1, G0 + s + 2)
    }
    PROC(aB0, aB1, b1, aA0, aA1)
    FINCOL(S - 2)
#pragma unroll
    for (int r = 0; r < 16; ++r) {
      float e0 = __builtin_amdgcn_exp2f(aB0[r]);
      float e1 = __builtin_amdgcn_exp2f(aB1[r]);
      rAcc0[r] += e0; rAcc1[r] += e1;
      colv += e0 + e1;
    }
    FINCOL(S - 1)
#undef PROC
#undef FINCOL

    __syncthreads();
    for (int idx = tid; idx < S * 32; idx += 128) {
      const int J = J0 + (idx >> 7);
      if (J != I)
        part[(size_t)I * MM + J * 128 + (idx & 127)] = colLds[0][idx] + colLds[1][idx];
    }

#pragma unroll
    for (int m = 1; m < 32; m <<= 1)
#pragma unroll
      for (int r = 0; r < 16; ++r) {
        rAcc0[r] += __shfl_xor(rAcc0[r], m, 32);
        rAcc1[r] += __shfl_xor(rAcc1[r], m, 32);
      }
    if ((lane & 31) == 0) {
      const int rbase = I * 128 + wave * 64;
#pragma unroll
      for (int r = 0; r < 16; ++r) {
        const int rl = (r & 3) + 8 * (r >> 2) + 4 * lh2;
        part[(size_t)(NBLK + q) * MM + rbase + rl] = rAcc0[r];
        part[(size_t)(NBLK + q) * MM + rbase + 32 + rl] = rAcc1[r];
      }
    }
  } else {
    // ================= own/pos path (r9, validated) =================
    const int bid2 = blockIdx.x - NBLK * NCHUNK;
    const int c = bid2 >> 1, q2 = bid2 & 1;
    const int Ga = c * 8 + q2 * 4 + wave * 2;
    const int c8 = c * 8;

    bf16x8 A0[8], A1[8];
#pragma unroll
    for (int kc = 0; kc < 8; ++kc) {
      A0[kc] = *(const bf16x8*)(F + (size_t)Ga * 8192 + kc * 1024 + lo16);
      A1[kc] = *(const bf16x8*)(F + (size_t)(Ga + 1) * 8192 + kc * 1024 + lo16);
    }
    bf16x8 b0[8], b1[8];
    float rAcc0[16], rAcc1[16];
#pragma unroll
    for (int r = 0; r < 16; ++r) { rAcc0[r] = 0.f; rAcc1[r] = 0.f; }

#define OWNTILE(BB_) {                                                         \
    f32x16 a0 = MFMA32(A0[0], BB_[0], Z), a1 = MFMA32(A1[0], BB_[0], Z);       \
    _Pragma("unroll")                                                          \
    for (int kc = 1; kc < 8; ++kc) {                                           \
      a0 = MFMA32(A0[kc], BB_[kc], a0); a1 = MFMA32(A1[kc], BB_[kc], a1); }    \
    _Pragma("unroll")                                                          \
    for (int r = 0; r < 16; ++r) {                                             \
      rAcc0[r] += __builtin_amdgcn_exp2f(a0[r]);                               \
      rAcc1[r] += __builtin_amdgcn_exp2f(a1[r]); } }

#define REDUCEW(DST) {                                                         \
    float t0[16], t1[16];                                                      \
    _Pragma("unroll")                                                          \
    for (int r = 0; r < 16; ++r) { t0[r] = rAcc0[r]; t1[r] = rAcc1[r]; }       \
    _Pragma("unroll")                                                          \
    for (int m = 1; m < 32; m <<= 1)                                           \
      _Pragma("unroll")                                                        \
      for (int r = 0; r < 16; ++r) {                                           \
        t0[r] += __shfl_xor(t0[r], m, 32);                                     \
        t1[r] += __shfl_xor(t1[r], m, 32); }                                   \
    if ((lane & 31) == 0) {                                                    \
      const int rbase = c * 256 + q2 * 128 + wave * 64;                        \
      _Pragma("unroll")                                                        \
      for (int r = 0; r < 16; ++r) {                                           \
        const int rl = (r & 3) + 8 * (r >> 2) + 4 * lh2;                       \
        DST[rbase + rl] = t0[r];                                               \
        DST[rbase + 32 + rl] = t1[r]; } } }

    LOADB(b0, c8 + 0)
    LOADB(b1, c8 + 1)  OWNTILE(b0)
    LOADB(b0, c8 + 2)  OWNTILE(b1)
    LOADB(b1, c8 + 3)  OWNTILE(b0)
    LOADB(b0, c8 + 4)  OWNTILE(b1)
    REDUCEW(posArr)
    LOADB(b1, c8 + 5)  OWNTILE(b0)
    LOADB(b0, c8 + 6)  OWNTILE(b1)
    LOADB(b1, c8 + 7)  OWNTILE(b0)
    OWNTILE(b1)
    REDUCEW(ownArr)
#undef OWNTILE
#undef REDUCEW
  }
#undef LOADB
}

// ---------------------------------------------------------------------------
// Kernel 5: per-row loss + block reduction + last-block mean (r11, validated).
// ---------------------------------------------------------------------------
__global__ void finalize_kernel(const float* __restrict__ part,
                                const float* __restrict__ ownArr,
                                const float* __restrict__ posArr,
                                float* __restrict__ partial,
                                int* __restrict__ ticket,
                                float* __restrict__ out) {
  __shared__ float red[4];
  const int t = threadIdx.x;
  const int p = blockIdx.x * 256 + t;
  const int pb = p >> 7;
  float a = 0.f;
  for (int b = 0; b < pb; ++b) a += part[(size_t)b * MM + p];
  const int qmax = (NBLK - 1 - pb) >> 3;
  for (int q = 0; q <= qmax; ++q) a += part[(size_t)(NBLK + q) * MM + p];
  float rl = logf(a - ownArr[p]) - logf(posArr[p]);
#pragma unroll
  for (int m = 1; m < 64; m <<= 1) rl += __shfl_xor(rl, m, 64);
  if ((t & 63) == 0) red[t >> 6] = rl;
  __syncthreads();
  if (t == 0) {
    const float bsum = red[0] + red[1] + red[2] + red[3];
    __hip_atomic_store(&partial[blockIdx.x], bsum, __ATOMIC_RELEASE,
                       __HIP_MEMORY_SCOPE_AGENT);
    const int old = __hip_atomic_fetch_add(ticket, 1, __ATOMIC_ACQ_REL,
                                           __HIP_MEMORY_SCOPE_AGENT);
    if (old == (MM / 256) - 1) {          // last block: deterministic sum
      float s = 0.f;
      for (int i = 0; i < MM / 256; ++i)
        s += __hip_atomic_load(&partial[i], __ATOMIC_ACQUIRE,
                               __HIP_MEMORY_SCOPE_AGENT);
      out[0] = s * (1.0f / MM);
    }
  }
}

extern "C" void kernel_launch(void* const* d_in, const int* in_sizes, int n_in,
                              void* d_out, int out_size, void* d_ws, size_t ws_size,
                              hipStream_t stream) {
  const float* prob = (const float*)d_in[0];
  const float* zi   = (const float*)d_in[1];
  const float* zj   = (const float*)d_in[2];
  float* out = (float*)d_out;

  char* ws = (char*)d_ws;
  char*  FT       = ws;                                  // 3,276,800 B
  float* part     = (float*)(ws + 3276800);              // 113*12800*4 = 5,785,600 B
  // cand buffers alias the (not-yet-live) part region: dead before sim writes.
  int*   candCnt  = (int*)  (ws + 3276800);              //    12,800 B
  int*   candIdx  = (int*)  (ws + 3276800 + 16384);      //   409,600 B
  float* candVal  = (float*)(ws + 3276800 + 430080);     //   409,600 B
  float* ownArr   = (float*)(ws + 9062400);              //    51,200 B
  float* posArr   = (float*)(ws + 9113600);              //    51,200 B
  float* partial  = (float*)(ws + 9164800);              //       256 B
  int*   ticket   = (int*)  (ws + 9165056);              //         4 B
  int*   topk     = (int*)  (ws + 9165312);              //    25,600 B

  cand_kernel    <<<NPART, 256, 0, stream>>>(prob, candCnt, candIdx, candVal, ticket);
  select_kernel  <<<CC, 256, 0, stream>>>(prob, candCnt, candIdx, candVal, topk);
  gather_norm    <<<MM / 4, 256, 0, stream>>>(zi, zj, topk, FT);
  sim_sym_kernel <<<NBLK * NCHUNK + 2 * CC, 128, 0, stream>>>(FT, part, ownArr, posArr);
  finalize_kernel<<<MM / 256, 256, 0, stream>>>(part, ownArr, posArr, partial, ticket, out);
}